// Round 4
// baseline (1827.446 us; speedup 1.0000x reference)
//
#include <hip/hip_runtime.h>

#define TT 4096
#define BB 128
#define L2E 1.4426950408889634f

typedef float v2f __attribute__((ext_vector_type(2)));
typedef float v4f __attribute__((ext_vector_type(4)));

__device__ __forceinline__ float fexp2(float a) {
  return __builtin_amdgcn_exp2f(a);  // v_exp_f32: 2^a
}

__device__ __forceinline__ unsigned long long hpair(float h, int k) {
  unsigned lo = (unsigned)__builtin_amdgcn_readlane(__float_as_int(h), k);
  unsigned hi = (unsigned)__builtin_amdgcn_readlane(__float_as_int(h), k + 1);
  return (unsigned long long)lo | ((unsigned long long)hi << 32);
}

// acc.{lo,hi} += w.{lo,hi} * h.{lo,hi}  -- packed dual-FP32, h from SGPR pair
__device__ __forceinline__ void pkfma(v2f& acc, v2f w, unsigned long long hs) {
  asm("v_pk_fma_f32 %0, %1, %2, %0" : "+v"(acc) : "v"(w), "s"(hs));
}

// One wave per batch element. Lane l owns gate rows j, 32+j, 64+j (j=l&31),
// full K=32 per lane (halves replicate; no cross-lane combine needed).
// Weight rows live in LDS (pre-scaled by log2e / 2log2e), re-read each step.
template <bool USE_WS>
__global__ __launch_bounds__(64, 1) void gru_seq(
    const float* __restrict__ x, const int* __restrict__ lengths,
    const float* __restrict__ w_ih, const float* __restrict__ w_hh,
    const float* __restrict__ b_ih, const float* __restrict__ b_hh,
    const float* __restrict__ fc_w, const float* __restrict__ fc_b,
    float* __restrict__ out, float* __restrict__ hbuf) {
  __shared__ float wlds[96 * 36];  // row stride 36 floats = 144B (16B aligned, 4-way banks)

  const int b = blockIdx.x;
  const int l = threadIdx.x;
  const int j = l & 31;
  const int half = l >> 5;
  const int len = lengths[b];

  // stage + pre-scale recurrent weights: rows 0..63 (r,z) * log2e, 64..95 (n) * 2log2e
  for (int i = l; i < 96 * 32; i += 64) {
    const int row = i >> 5, k = i & 31;
    const float s = (row < 64) ? L2E : (2.0f * L2E);
    wlds[row * 36 + k] = w_hh[i] * s;
  }

  // x-side weights (pairs, pre-scaled)
  v2f wxr[3], wxz[3], wxn[3];
#pragma unroll
  for (int i = 0; i < 3; ++i) {
    wxr[i] = v2f{w_ih[j * 6 + 2 * i], w_ih[j * 6 + 2 * i + 1]} * L2E;
    wxz[i] = v2f{w_ih[(32 + j) * 6 + 2 * i], w_ih[(32 + j) * 6 + 2 * i + 1]} * L2E;
    wxn[i] = v2f{w_ih[(64 + j) * 6 + 2 * i], w_ih[(64 + j) * 6 + 2 * i + 1]} * (2.0f * L2E);
  }
  const float br  = (b_ih[j] + b_hh[j]) * L2E;
  const float bz  = (b_ih[32 + j] + b_hh[32 + j]) * L2E;
  const float bxn = b_ih[64 + j] * (2.0f * L2E);
  const float bhn = b_hh[64 + j] * (2.0f * L2E);
  const float fcw = fc_w[half * 32 + j];  // fallback path only
  const float fcb = fc_b[half];

  const float* xb = x + (size_t)b * (TT * 6);
  float* hrow = hbuf + (size_t)b * (TT * 32);
  float* ob = out + (size_t)b * (TT * 2);

  __syncthreads();

  const v4f* rq = (const v4f*)(wlds + j * 36);
  const v4f* zq = (const v4f*)(wlds + (32 + j) * 36);
  const v4f* nq = (const v4f*)(wlds + (64 + j) * 36);

  float h = 0.0f;
  v2f cx[3], nx[3];
  {
    const v2f* xp = (const v2f*)xb;
    cx[0] = xp[0]; cx[1] = xp[1]; cx[2] = xp[2];
  }

  for (int t = 0; t < len; ++t) {
    // prefetch next x (8B vector loads, one full step of latency slack)
    const int tn = (t + 1 < len) ? (t + 1) : t;
    const v2f* xp = (const v2f*)(xb + tn * 6);
    nx[0] = xp[0]; nx[1] = xp[1]; nx[2] = xp[2];

    // x-side gate contributions (independent of h; fills broadcast latency)
    v2f axr = {br, 0.f}, axz = {bz, 0.f}, axn = {bxn, 0.f};
#pragma unroll
    for (int i = 0; i < 3; ++i) {
      axr += wxr[i] * cx[i];
      axz += wxz[i] * cx[i];
      axn += wxn[i] * cx[i];
    }

    // broadcast h as 16 SGPR pairs (VALU readlane + SALU pack, no LDS pipe)
    unsigned long long hp[16];
#pragma unroll
    for (int i = 0; i < 16; ++i) hp[i] = hpair(h, 2 * i);

    // 96 MACs as 48 v_pk_fma_f32; weights streamed from LDS (24 ds_read_b128)
    v2f ar0 = axr, ar1 = {0.f, 0.f};
    v2f az0 = axz, az1 = {0.f, 0.f};
    v2f an0 = {bhn, 0.f}, an1 = {0.f, 0.f};
#pragma unroll
    for (int q = 0; q < 8; ++q) {
      const v4f wr4 = rq[q], wz4 = zq[q], wn4 = nq[q];
      const v2f wrlo = {wr4[0], wr4[1]}, wrhi = {wr4[2], wr4[3]};
      const v2f wzlo = {wz4[0], wz4[1]}, wzhi = {wz4[2], wz4[3]};
      const v2f wnlo = {wn4[0], wn4[1]}, wnhi = {wn4[2], wn4[3]};
      pkfma(ar0, wrlo, hp[2 * q]);
      pkfma(az0, wzlo, hp[2 * q]);
      pkfma(an0, wnlo, hp[2 * q]);
      pkfma(ar1, wrhi, hp[2 * q + 1]);
      pkfma(az1, wzhi, hp[2 * q + 1]);
      pkfma(an1, wnhi, hp[2 * q + 1]);
    }
    const v2f arc = ar0 + ar1, azc = az0 + az1, anc = an0 + an1;
    const float sr = arc[0] + arc[1];            // already *log2e
    const float sz = azc[0] + azc[1];
    const float hn = anc[0] + anc[1];            // already *2log2e (incl bhn)
    const float xn = axn[0] + axn[1];            // already *2log2e (incl bxn)

    // r = sigmoid(sr/log2e) = rcp(1+exp2(-sr)); tanh(a) = 2*rcp(1+exp2(-2a*log2e))-1
    const float r = __builtin_amdgcn_rcpf(1.0f + fexp2(-sr));
    const float z = __builtin_amdgcn_rcpf(1.0f + fexp2(-sz));
    const float ap = fmaf(r, hn, xn);
    const float qq = __builtin_amdgcn_rcpf(1.0f + fexp2(-ap));
    const float n = fmaf(2.0f, qq, -1.0f);
    const float hnew = fmaf(n, 1.0f - z, z * h);
    h = hnew;

    if constexpr (USE_WS) {
      if (half == 0) hrow[t * 32 + j] = hnew;  // fire-and-forget 128B store
    } else {
      float p = hnew * fcw;
      p += __shfl_xor(p, 1);
      p += __shfl_xor(p, 2);
      p += __shfl_xor(p, 4);
      p += __shfl_xor(p, 8);
      p += __shfl_xor(p, 16);
      if (j == 0) ob[t * 2 + half] = p + fcb;
    }

#pragma unroll
    for (int i = 0; i < 3; ++i) cx[i] = nx[i];
  }

  if constexpr (!USE_WS) {
    const float fb0 = fc_b[0], fb1 = fc_b[1];
    for (int idx = len * 2 + l; idx < TT * 2; idx += 64)
      ob[idx] = (idx & 1) ? fb1 : fb0;
  }
}

// out[b,t,:] = (t < len[b]) ? h[b,t,:] @ fc_w^T + fc_b : fc_b
__global__ __launch_bounds__(256) void fc_apply(
    const float* __restrict__ hbuf, const int* __restrict__ lengths,
    const float* __restrict__ fc_w, const float* __restrict__ fc_b,
    float* __restrict__ out) {
  const int idx = blockIdx.x * 256 + threadIdx.x;  // flattened (b,t)
  const int b = idx >> 12;
  const int t = idx & (TT - 1);
  const float fb0 = fc_b[0], fb1 = fc_b[1];
  float* op = out + (size_t)idx * 2;
  if (t >= lengths[b]) {
    op[0] = fb0;
    op[1] = fb1;
    return;
  }
  const float4* hp = (const float4*)(hbuf + (size_t)idx * 32);
  const float4* w0 = (const float4*)(fc_w);
  const float4* w1 = (const float4*)(fc_w + 32);
  float o0 = 0.f, o1 = 0.f;
#pragma unroll
  for (int q = 0; q < 8; ++q) {
    const float4 hv = hp[q], a = w0[q], c = w1[q];
    o0 += hv.x * a.x + hv.y * a.y + hv.z * a.z + hv.w * a.w;
    o1 += hv.x * c.x + hv.y * c.y + hv.z * c.z + hv.w * c.w;
  }
  op[0] = o0 + fb0;
  op[1] = o1 + fb1;
}

extern "C" void kernel_launch(void* const* d_in, const int* in_sizes, int n_in,
                              void* d_out, int out_size, void* d_ws, size_t ws_size,
                              hipStream_t stream) {
  const float* x       = (const float*)d_in[0];
  const int*   lengths = (const int*)d_in[1];
  const float* w_ih    = (const float*)d_in[2];
  const float* w_hh    = (const float*)d_in[3];
  const float* b_ih    = (const float*)d_in[4];
  const float* b_hh    = (const float*)d_in[5];
  const float* fc_w    = (const float*)d_in[6];
  const float* fc_b    = (const float*)d_in[7];
  float* outp = (float*)d_out;

  const size_t need = (size_t)BB * TT * 32 * sizeof(float);  // 64 MB
  if (ws_size >= need) {
    float* hbuf = (float*)d_ws;
    hipLaunchKernelGGL(gru_seq<true>, dim3(BB), dim3(64), 0, stream,
                       x, lengths, w_ih, w_hh, b_ih, b_hh, fc_w, fc_b, outp, hbuf);
    hipLaunchKernelGGL(fc_apply, dim3((BB * TT) / 256), dim3(256), 0, stream,
                       hbuf, lengths, fc_w, fc_b, outp);
  } else {
    hipLaunchKernelGGL(gru_seq<false>, dim3(BB), dim3(64), 0, stream,
                       x, lengths, w_ih, w_hh, b_ih, b_hh, fc_w, fc_b, outp, nullptr);
  }
}